// Round 7
// baseline (112.613 us; speedup 1.0000x reference)
//
#include <hip/hip_runtime.h>

#define N_NODES 50000
#define N_EDGES 800000
#define FEAT    128

#define NRANGE  4
#define NSLICE  64
#define NBLK    (NRANGE * NSLICE)        // 256 blocks, 1/CU
#define RNODES  (N_NODES / NRANGE)       // 12500 nodes/range -> 50 KB LDS
#define RGROUPS (RNODES / 4)             // 3125 float4 groups per range
#define NGROUPS (N_NODES / 4)            // 12500 float4 groups total
#define GPB     ((NGROUPS + NBLK - 1) / NBLK)  // 49 groups per block in reduce
#define SLICE_Q (N_EDGES / NSLICE / 4)   // 3125 quads per slice
#define TB      1024

// ws layout: partial[NBLK][RNODES] f32 | sum f32 | bar u32 | ticket u32

__global__ void init_ctl(float* sum, unsigned* bar, unsigned* ticket) {
    *sum = 0.0f; *bar = 0u; *ticket = 0u;
}

__global__ __launch_bounds__(TB) void fused(
        const float* __restrict__ li,
        const float* __restrict__ w,
        const int* __restrict__ row,
        const int* __restrict__ col,
        float* __restrict__ partial,
        float* sum, unsigned* bar, unsigned* ticket,
        float* __restrict__ out) {
    __shared__ float accl[RNODES];                 // 50 KB
    __shared__ float smr[TB / 64];
    // slice = low bits so the 4 sibling blocks (same slice, 4 ranges) satisfy
    // b%8 == s%8 -> same XCD -> slice re-read served by that XCD's L2.
    const int s  = blockIdx.x & (NSLICE - 1);
    const int r  = blockIdx.x >> 6;
    const int lo = r * RNODES;

    // ---- phase A: zero LDS, stream slice, LDS-atomic accumulate ----
    float4* az = (float4*)accl;
    for (int i = threadIdx.x; i < RGROUPS; i += TB)
        az[i] = make_float4(0.f, 0.f, 0.f, 0.f);
    __syncthreads();

    const float4* wq = (const float4*)w   + (size_t)s * SLICE_Q;
    const int4*   rq = (const int4*)row   + (size_t)s * SLICE_Q;
    const int4*   cq = (const int4*)col   + (size_t)s * SLICE_Q;

    for (int q = threadIdx.x; q < SLICE_Q; q += TB) {
        float4 wv = wq[q];
        int4   rv = rq[q];
        int4   cv = cq[q];
        int a;
        a = rv.x - lo; if ((unsigned)a < RNODES) atomicAdd(&accl[a], wv.x * li[(size_t)cv.x * FEAT]);
        a = rv.y - lo; if ((unsigned)a < RNODES) atomicAdd(&accl[a], wv.y * li[(size_t)cv.y * FEAT]);
        a = rv.z - lo; if ((unsigned)a < RNODES) atomicAdd(&accl[a], wv.z * li[(size_t)cv.z * FEAT]);
        a = rv.w - lo; if ((unsigned)a < RNODES) atomicAdd(&accl[a], wv.w * li[(size_t)cv.w * FEAT]);
    }
    __syncthreads();

    // ---- phase B: flush 50 KB partial ----
    float4* pdst = (float4*)(partial + (size_t)blockIdx.x * RNODES);
    for (int i = threadIdx.x; i < RGROUPS; i += TB) pdst[i] = az[i];

    // ---- grid barrier (all 256 blocks co-resident: 1024 thr + 50 KB LDS) ----
    __syncthreads();
    if (threadIdx.x == 0) {
        __threadfence();                           // release partial writes
        atomicAdd(bar, 1u);
        while (__hip_atomic_load(bar, __ATOMIC_RELAXED, __HIP_MEMORY_SCOPE_AGENT) < NBLK)
            __builtin_amdgcn_s_sleep(2);
    }
    __syncthreads();
    __threadfence();                               // acquire before partial reads

    // ---- phase C: per-node sum of 64 slice-partials, relu, global sum ----
    const int team = threadIdx.x >> 4;             // 64 teams of 16 lanes
    const int ln   = threadIdx.x & 15;
    float local = 0.0f;
    int g = blockIdx.x * GPB + team;               // one group (4 nodes) per team
    if (team < GPB && g < NGROUPS) {
        int rr = g / RGROUPS;
        int gl = g - rr * RGROUPS;
        const float4* base = (const float4*)(partial + (size_t)(rr * NSLICE) * RNODES) + gl;
        float ax = 0.f, ay = 0.f, az4 = 0.f, aw = 0.f;
        #pragma unroll
        for (int pb = 0; pb < 4; ++pb) {
            float4 p = base[(size_t)(ln + pb * 16) * RGROUPS];
            ax += p.x; ay += p.y; az4 += p.z; aw += p.w;
        }
        #pragma unroll
        for (int d = 8; d > 0; d >>= 1) {
            ax  += __shfl_down(ax,  d, 16);
            ay  += __shfl_down(ay,  d, 16);
            az4 += __shfl_down(az4, d, 16);
            aw  += __shfl_down(aw,  d, 16);
        }
        if (ln == 0)
            local = fmaxf(ax, 0.f) + fmaxf(ay, 0.f) +
                    fmaxf(az4, 0.f) + fmaxf(aw, 0.f);
    }
    #pragma unroll
    for (int off = 32; off > 0; off >>= 1)
        local += __shfl_down(local, off, 64);
    if ((threadIdx.x & 63) == 0) smr[threadIdx.x >> 6] = local;
    __syncthreads();
    if (threadIdx.x == 0) {
        float t = 0.f;
        #pragma unroll
        for (int i = 0; i < TB / 64; ++i) t += smr[i];
        atomicAdd(sum, t);
        __threadfence();
        unsigned old = atomicAdd(ticket, 1u);
        if (old == NBLK - 1) {                     // last block finalizes
            float v = __hip_atomic_load(sum, __ATOMIC_RELAXED, __HIP_MEMORY_SCOPE_AGENT);
            out[0] = 1.0f / (1.0f + expf(-v));
        }
    }
}

// ---------------- fallback (tiny ws): global atomics ----------------

__global__ void zero_acc(float* __restrict__ acc, float* sum, unsigned* ticket) {
    int i = blockIdx.x * blockDim.x + threadIdx.x;
    if (i < N_NODES) acc[i] = 0.0f;
    if (i == 0) { *sum = 0.0f; *ticket = 0u; }
}

__global__ void edge_scatter4(const float* __restrict__ li,
                              const float* __restrict__ w,
                              const int* __restrict__ row,
                              const int* __restrict__ col,
                              float* __restrict__ acc) {
    int t = blockIdx.x * blockDim.x + threadIdx.x;
    if (t < N_EDGES / 4) {
        float4 wv = ((const float4*)w)[t];
        int4   rv = ((const int4*)row)[t];
        int4   cv = ((const int4*)col)[t];
        atomicAdd(&acc[rv.x], wv.x * li[(size_t)cv.x * FEAT]);
        atomicAdd(&acc[rv.y], wv.y * li[(size_t)cv.y * FEAT]);
        atomicAdd(&acc[rv.z], wv.z * li[(size_t)cv.z * FEAT]);
        atomicAdd(&acc[rv.w], wv.w * li[(size_t)cv.w * FEAT]);
    }
}

__global__ void relu_sum_fin(const float* __restrict__ acc,
                             float* __restrict__ sum,
                             unsigned* __restrict__ ticket,
                             float* __restrict__ out) {
    float local = 0.0f;
    for (int i = blockIdx.x * blockDim.x + threadIdx.x; i < N_NODES / 4;
         i += gridDim.x * blockDim.x) {
        float4 a = ((const float4*)acc)[i];
        local += fmaxf(a.x, 0.f) + fmaxf(a.y, 0.f) +
                 fmaxf(a.z, 0.f) + fmaxf(a.w, 0.f);
    }
    #pragma unroll
    for (int off = 32; off > 0; off >>= 1)
        local += __shfl_down(local, off, 64);
    __shared__ float sm[4];
    if ((threadIdx.x & 63) == 0) sm[threadIdx.x >> 6] = local;
    __syncthreads();
    if (threadIdx.x == 0) {
        atomicAdd(sum, sm[0] + sm[1] + sm[2] + sm[3]);
        __threadfence();
        unsigned old = atomicAdd(ticket, 1u);
        if (old == gridDim.x - 1) {
            float v = __hip_atomic_load(sum, __ATOMIC_RELAXED, __HIP_MEMORY_SCOPE_AGENT);
            out[0] = 1.0f / (1.0f + expf(-v));
        }
    }
}

extern "C" void kernel_launch(void* const* d_in, const int* in_sizes, int n_in,
                              void* d_out, int out_size, void* d_ws, size_t ws_size,
                              hipStream_t stream) {
    const float* li  = (const float*)d_in[0];
    const float* w   = (const float*)d_in[1];
    const int*   row = (const int*)d_in[2];
    const int*   col = (const int*)d_in[3];
    float* out = (float*)d_out;

    size_t need = (size_t)NBLK * RNODES * 4 + 16;

    if (ws_size >= need) {
        float*    partial = (float*)d_ws;
        float*    sum     = partial + (size_t)NBLK * RNODES;
        unsigned* bar     = (unsigned*)(sum + 1);
        unsigned* ticket  = bar + 1;

        init_ctl<<<1, 1, 0, stream>>>(sum, bar, ticket);
        fused<<<NBLK, TB, 0, stream>>>(li, w, row, col, partial, sum, bar, ticket, out);
    } else {
        float*    acc    = (float*)d_ws;
        float*    sum    = acc + N_NODES;
        unsigned* ticket = (unsigned*)(sum + 1);

        zero_acc<<<(N_NODES + 255) / 256, 256, 0, stream>>>(acc, sum, ticket);
        edge_scatter4<<<(N_EDGES / 4 + 255) / 256, 256, 0, stream>>>(li, w, row, col, acc);
        relu_sum_fin<<<49, 256, 0, stream>>>(acc, sum, ticket, out);
    }
}

// Round 8
// 111.675 us; speedup vs baseline: 1.0084x; 1.0084x over previous
//
#include <hip/hip_runtime.h>

#define N_NODES 50000
#define N_EDGES 800000
#define FEAT    128

#define NRANGE  8
#define NSLICE  32
#define NBLK    (NRANGE * NSLICE)      // 256 blocks, 1/CU
#define RN_REAL (N_NODES / NRANGE)     // 6250 nodes per range
#define RNP     6400                   // padded stride (25.6 KB LDS, /4 clean)
#define RGROUPS (RNP / 4)              // 1600 float4 groups
#define SLICE_Q (N_EDGES / NSLICE / 4) // 6250 quads per slice
#define TB      1024
#define NPB     ((N_NODES + NBLK - 1) / NBLK)  // 196 nodes per block (reduce)

// ws layout: partial[NBLK][RNP] f32 | li0[N_NODES] f32 | sum f32 | bar u32 | ticket u32

__global__ void pack_init(const float* __restrict__ li,
                          float* __restrict__ li0,
                          float* sum, unsigned* bar, unsigned* ticket) {
    int i = blockIdx.x * blockDim.x + threadIdx.x;
    if (i < N_NODES) li0[i] = li[(size_t)i * FEAT];   // pack feature column 0
    if (i == 0) { *sum = 0.0f; *bar = 0u; *ticket = 0u; }
}

__global__ __launch_bounds__(TB) void fused(
        const float* __restrict__ li0,
        const float* __restrict__ w,
        const int* __restrict__ row,
        const int* __restrict__ col,
        float* __restrict__ partial,
        float* sum, unsigned* bar, unsigned* ticket,
        float* __restrict__ out) {
    __shared__ float accl[RNP];                    // 25.6 KB
    __shared__ float smr[TB / 64];
    // slice = low bits: the 8 sibling blocks of a slice (one per range) have
    // b%8 == s%8 -> same XCD -> slice re-read is L2-served after first fetch.
    const int s  = blockIdx.x & (NSLICE - 1);
    const int r  = blockIdx.x >> 5;
    const int lo = r * RN_REAL;

    // ---- phase A: zero LDS, stream slice, LDS-atomic accumulate ----
    float4* az = (float4*)accl;
    for (int i = threadIdx.x; i < RGROUPS; i += TB)
        az[i] = make_float4(0.f, 0.f, 0.f, 0.f);
    __syncthreads();

    const float4* wq = (const float4*)w   + (size_t)s * SLICE_Q;
    const int4*   rq = (const int4*)row   + (size_t)s * SLICE_Q;
    const int4*   cq = (const int4*)col   + (size_t)s * SLICE_Q;

    for (int q = threadIdx.x; q < SLICE_Q; q += TB) {
        float4 wv = wq[q];
        int4   rv = rq[q];
        int4   cv = cq[q];
        int a;
        a = rv.x - lo; if ((unsigned)a < RN_REAL) atomicAdd(&accl[a], wv.x * li0[cv.x]);
        a = rv.y - lo; if ((unsigned)a < RN_REAL) atomicAdd(&accl[a], wv.y * li0[cv.y]);
        a = rv.z - lo; if ((unsigned)a < RN_REAL) atomicAdd(&accl[a], wv.z * li0[cv.z]);
        a = rv.w - lo; if ((unsigned)a < RN_REAL) atomicAdd(&accl[a], wv.w * li0[cv.w]);
    }
    __syncthreads();

    // ---- phase B: flush 25.6 KB partial (pad region holds zeros) ----
    float4* pdst = (float4*)(partial + (size_t)blockIdx.x * RNP);
    for (int i = threadIdx.x; i < RGROUPS; i += TB) pdst[i] = az[i];

    // ---- grid barrier (256 blocks; capacity 2 blocks/CU -> no deadlock) ----
    __syncthreads();
    if (threadIdx.x == 0) {
        __threadfence();                           // release partial writes
        atomicAdd(bar, 1u);
        while (__hip_atomic_load(bar, __ATOMIC_RELAXED, __HIP_MEMORY_SCOPE_AGENT) < NBLK)
            __builtin_amdgcn_s_sleep(2);
    }
    __syncthreads();
    __threadfence();                               // acquire before partial reads

    // ---- phase C: per-node sum of 32 slice-partials, relu, global sum ----
    float local = 0.0f;
    int n = blockIdx.x * NPB + threadIdx.x;        // NPB=196 < TB: one node/thread
    if (threadIdx.x < NPB && n < N_NODES) {
        int rr = n / RN_REAL;
        int nl = n - rr * RN_REAL;
        const float* base = partial + (size_t)(rr * NSLICE) * RNP + nl;
        float a0 = 0.f, a1 = 0.f, a2 = 0.f, a3 = 0.f;
        #pragma unroll
        for (int b = 0; b < NSLICE; b += 4) {
            a0 += base[(size_t)(b + 0) * RNP];
            a1 += base[(size_t)(b + 1) * RNP];
            a2 += base[(size_t)(b + 2) * RNP];
            a3 += base[(size_t)(b + 3) * RNP];
        }
        local = fmaxf(a0 + a1 + a2 + a3, 0.f);
    }
    #pragma unroll
    for (int off = 32; off > 0; off >>= 1)
        local += __shfl_down(local, off, 64);
    if ((threadIdx.x & 63) == 0) smr[threadIdx.x >> 6] = local;
    __syncthreads();
    if (threadIdx.x == 0) {
        float t = 0.f;
        #pragma unroll
        for (int i = 0; i < TB / 64; ++i) t += smr[i];
        atomicAdd(sum, t);
        __threadfence();
        unsigned old = atomicAdd(ticket, 1u);
        if (old == NBLK - 1) {                     // last block finalizes
            float v = __hip_atomic_load(sum, __ATOMIC_RELAXED, __HIP_MEMORY_SCOPE_AGENT);
            out[0] = 1.0f / (1.0f + expf(-v));
        }
    }
}

// ---------------- fallback (tiny ws): global atomics ----------------

__global__ void zero_acc(float* __restrict__ acc, float* sum, unsigned* ticket) {
    int i = blockIdx.x * blockDim.x + threadIdx.x;
    if (i < N_NODES) acc[i] = 0.0f;
    if (i == 0) { *sum = 0.0f; *ticket = 0u; }
}

__global__ void edge_scatter4(const float* __restrict__ li,
                              const float* __restrict__ w,
                              const int* __restrict__ row,
                              const int* __restrict__ col,
                              float* __restrict__ acc) {
    int t = blockIdx.x * blockDim.x + threadIdx.x;
    if (t < N_EDGES / 4) {
        float4 wv = ((const float4*)w)[t];
        int4   rv = ((const int4*)row)[t];
        int4   cv = ((const int4*)col)[t];
        atomicAdd(&acc[rv.x], wv.x * li[(size_t)cv.x * FEAT]);
        atomicAdd(&acc[rv.y], wv.y * li[(size_t)cv.y * FEAT]);
        atomicAdd(&acc[rv.z], wv.z * li[(size_t)cv.z * FEAT]);
        atomicAdd(&acc[rv.w], wv.w * li[(size_t)cv.w * FEAT]);
    }
}

__global__ void relu_sum_fin(const float* __restrict__ acc,
                             float* __restrict__ sum,
                             unsigned* __restrict__ ticket,
                             float* __restrict__ out) {
    float local = 0.0f;
    for (int i = blockIdx.x * blockDim.x + threadIdx.x; i < N_NODES / 4;
         i += gridDim.x * blockDim.x) {
        float4 a = ((const float4*)acc)[i];
        local += fmaxf(a.x, 0.f) + fmaxf(a.y, 0.f) +
                 fmaxf(a.z, 0.f) + fmaxf(a.w, 0.f);
    }
    #pragma unroll
    for (int off = 32; off > 0; off >>= 1)
        local += __shfl_down(local, off, 64);
    __shared__ float sm[4];
    if ((threadIdx.x & 63) == 0) sm[threadIdx.x >> 6] = local;
    __syncthreads();
    if (threadIdx.x == 0) {
        atomicAdd(sum, sm[0] + sm[1] + sm[2] + sm[3]);
        __threadfence();
        unsigned old = atomicAdd(ticket, 1u);
        if (old == gridDim.x - 1) {
            float v = __hip_atomic_load(sum, __ATOMIC_RELAXED, __HIP_MEMORY_SCOPE_AGENT);
            out[0] = 1.0f / (1.0f + expf(-v));
        }
    }
}

extern "C" void kernel_launch(void* const* d_in, const int* in_sizes, int n_in,
                              void* d_out, int out_size, void* d_ws, size_t ws_size,
                              hipStream_t stream) {
    const float* li  = (const float*)d_in[0];
    const float* w   = (const float*)d_in[1];
    const int*   row = (const int*)d_in[2];
    const int*   col = (const int*)d_in[3];
    float* out = (float*)d_out;

    size_t need = (size_t)NBLK * RNP * 4 + (size_t)N_NODES * 4 + 16;

    if (ws_size >= need) {
        float*    partial = (float*)d_ws;
        float*    li0     = partial + (size_t)NBLK * RNP;
        float*    sum     = li0 + N_NODES;
        unsigned* bar     = (unsigned*)(sum + 1);
        unsigned* ticket  = bar + 1;

        pack_init<<<(N_NODES + 255) / 256, 256, 0, stream>>>(li, li0, sum, bar, ticket);
        fused<<<NBLK, TB, 0, stream>>>(li0, w, row, col, partial, sum, bar, ticket, out);
    } else {
        float*    acc    = (float*)d_ws;
        float*    sum    = acc + N_NODES;
        unsigned* ticket = (unsigned*)(sum + 1);

        zero_acc<<<(N_NODES + 255) / 256, 256, 0, stream>>>(acc, sum, ticket);
        edge_scatter4<<<(N_EDGES / 4 + 255) / 256, 256, 0, stream>>>(li, w, row, col, acc);
        relu_sum_fin<<<49, 256, 0, stream>>>(acc, sum, ticket, out);
    }
}

// Round 9
// 29.958 us; speedup vs baseline: 3.7590x; 3.7277x over previous
//
#include <hip/hip_runtime.h>

#define N_NODES 50000
#define N_EDGES 800000
#define FEAT    128

#define NRANGE  8
#define NSLICE  32
#define NBLK    (NRANGE * NSLICE)      // 256 accum blocks, 1/CU
#define RN_REAL (N_NODES / NRANGE)     // 6250 nodes per range
#define RNP     6400                   // padded LDS/partial stride (25.6 KB)
#define RGROUPS (RNP / 4)              // 1600 float4 groups
#define SLICE_Q (N_EDGES / NSLICE / 4) // 6250 quads per slice
#define TB      1024

// ws layout: partial[NBLK][RNP] f32 | li0[N_NODES] f32 | sum f32 | ticket u32

__global__ void pack_init(const float* __restrict__ li,
                          float* __restrict__ li0,
                          float* sum, unsigned* ticket) {
    int i = blockIdx.x * blockDim.x + threadIdx.x;
    if (i < N_NODES) li0[i] = li[(size_t)i * FEAT];   // pack feature column 0
    if (i == 0) { *sum = 0.0f; *ticket = 0u; }
}

// accum: block (r,s) filters slice s's edges to node-range r in LDS.
// siblings of a slice (same s, all r) share b%8 == s%8 -> same XCD ->
// the 8x edge re-read is served by that XCD's L2.
__global__ __launch_bounds__(TB) void range_accum(
        const float* __restrict__ li0,
        const float* __restrict__ w,
        const int* __restrict__ row,
        const int* __restrict__ col,
        float* __restrict__ partial) {
    __shared__ float accl[RNP];                    // 25.6 KB
    const int s  = blockIdx.x & (NSLICE - 1);
    const int r  = blockIdx.x >> 5;
    const int lo = r * RN_REAL;

    float4* az = (float4*)accl;
    for (int i = threadIdx.x; i < RGROUPS; i += TB)
        az[i] = make_float4(0.f, 0.f, 0.f, 0.f);
    __syncthreads();

    const float4* wq = (const float4*)w   + (size_t)s * SLICE_Q;
    const int4*   rq = (const int4*)row   + (size_t)s * SLICE_Q;
    const int4*   cq = (const int4*)col   + (size_t)s * SLICE_Q;

    for (int q = threadIdx.x; q < SLICE_Q; q += TB) {
        float4 wv = wq[q];
        int4   rv = rq[q];
        int4   cv = cq[q];
        int a;
        a = rv.x - lo; if ((unsigned)a < RN_REAL) atomicAdd(&accl[a], wv.x * li0[cv.x]);
        a = rv.y - lo; if ((unsigned)a < RN_REAL) atomicAdd(&accl[a], wv.y * li0[cv.y]);
        a = rv.z - lo; if ((unsigned)a < RN_REAL) atomicAdd(&accl[a], wv.z * li0[cv.z]);
        a = rv.w - lo; if ((unsigned)a < RN_REAL) atomicAdd(&accl[a], wv.w * li0[cv.w]);
    }
    __syncthreads();

    float4* pdst = (float4*)(partial + (size_t)blockIdx.x * RNP);
    for (int i = threadIdx.x; i < RGROUPS; i += TB) pdst[i] = az[i];
}

// reduce: one node per thread; sum 32 slice-partials, relu, block-reduce,
// ticket-gated sigmoid finalize (no extra launch).
__global__ void reduce_fin(const float* __restrict__ partial,
                           float* __restrict__ sum,
                           unsigned* __restrict__ ticket,
                           float* __restrict__ out) {
    int n = blockIdx.x * blockDim.x + threadIdx.x;
    float local = 0.0f;
    if (n < N_NODES) {
        int rr = n / RN_REAL;
        int nl = n - rr * RN_REAL;
        const float* base = partial + (size_t)(rr * NSLICE) * RNP + nl;
        float a0 = 0.f, a1 = 0.f, a2 = 0.f, a3 = 0.f;
        #pragma unroll
        for (int b = 0; b < NSLICE; b += 4) {
            a0 += base[(size_t)(b + 0) * RNP];
            a1 += base[(size_t)(b + 1) * RNP];
            a2 += base[(size_t)(b + 2) * RNP];
            a3 += base[(size_t)(b + 3) * RNP];
        }
        local = fmaxf(a0 + a1 + a2 + a3, 0.f);
    }
    #pragma unroll
    for (int off = 32; off > 0; off >>= 1)
        local += __shfl_down(local, off, 64);
    __shared__ float sm[4];
    if ((threadIdx.x & 63) == 0) sm[threadIdx.x >> 6] = local;
    __syncthreads();
    if (threadIdx.x == 0) {
        atomicAdd(sum, sm[0] + sm[1] + sm[2] + sm[3]);
        __threadfence();
        unsigned old = atomicAdd(ticket, 1u);
        if (old == gridDim.x - 1) {
            float v = __hip_atomic_load(sum, __ATOMIC_RELAXED, __HIP_MEMORY_SCOPE_AGENT);
            out[0] = 1.0f / (1.0f + expf(-v));
        }
    }
}

// ---------------- fallback (tiny ws): global atomics ----------------

__global__ void zero_acc(float* __restrict__ acc, float* sum, unsigned* ticket) {
    int i = blockIdx.x * blockDim.x + threadIdx.x;
    if (i < N_NODES) acc[i] = 0.0f;
    if (i == 0) { *sum = 0.0f; *ticket = 0u; }
}

__global__ void edge_scatter4(const float* __restrict__ li,
                              const float* __restrict__ w,
                              const int* __restrict__ row,
                              const int* __restrict__ col,
                              float* __restrict__ acc) {
    int t = blockIdx.x * blockDim.x + threadIdx.x;
    if (t < N_EDGES / 4) {
        float4 wv = ((const float4*)w)[t];
        int4   rv = ((const int4*)row)[t];
        int4   cv = ((const int4*)col)[t];
        atomicAdd(&acc[rv.x], wv.x * li[(size_t)cv.x * FEAT]);
        atomicAdd(&acc[rv.y], wv.y * li[(size_t)cv.y * FEAT]);
        atomicAdd(&acc[rv.z], wv.z * li[(size_t)cv.z * FEAT]);
        atomicAdd(&acc[rv.w], wv.w * li[(size_t)cv.w * FEAT]);
    }
}

__global__ void relu_sum_fin(const float* __restrict__ acc,
                             float* __restrict__ sum,
                             unsigned* __restrict__ ticket,
                             float* __restrict__ out) {
    float local = 0.0f;
    for (int i = blockIdx.x * blockDim.x + threadIdx.x; i < N_NODES / 4;
         i += gridDim.x * blockDim.x) {
        float4 a = ((const float4*)acc)[i];
        local += fmaxf(a.x, 0.f) + fmaxf(a.y, 0.f) +
                 fmaxf(a.z, 0.f) + fmaxf(a.w, 0.f);
    }
    #pragma unroll
    for (int off = 32; off > 0; off >>= 1)
        local += __shfl_down(local, off, 64);
    __shared__ float sm[4];
    if ((threadIdx.x & 63) == 0) sm[threadIdx.x >> 6] = local;
    __syncthreads();
    if (threadIdx.x == 0) {
        atomicAdd(sum, sm[0] + sm[1] + sm[2] + sm[3]);
        __threadfence();
        unsigned old = atomicAdd(ticket, 1u);
        if (old == gridDim.x - 1) {
            float v = __hip_atomic_load(sum, __ATOMIC_RELAXED, __HIP_MEMORY_SCOPE_AGENT);
            out[0] = 1.0f / (1.0f + expf(-v));
        }
    }
}

extern "C" void kernel_launch(void* const* d_in, const int* in_sizes, int n_in,
                              void* d_out, int out_size, void* d_ws, size_t ws_size,
                              hipStream_t stream) {
    const float* li  = (const float*)d_in[0];
    const float* w   = (const float*)d_in[1];
    const int*   row = (const int*)d_in[2];
    const int*   col = (const int*)d_in[3];
    float* out = (float*)d_out;

    size_t need = (size_t)NBLK * RNP * 4 + (size_t)N_NODES * 4 + 16;

    if (ws_size >= need) {
        float*    partial = (float*)d_ws;
        float*    li0     = partial + (size_t)NBLK * RNP;
        float*    sum     = li0 + N_NODES;
        unsigned* ticket  = (unsigned*)(sum + 1);

        pack_init<<<(N_NODES + 255) / 256, 256, 0, stream>>>(li, li0, sum, ticket);
        range_accum<<<NBLK, TB, 0, stream>>>(li0, w, row, col, partial);
        reduce_fin<<<(N_NODES + 255) / 256, 256, 0, stream>>>(partial, sum, ticket, out);
    } else {
        float*    acc    = (float*)d_ws;
        float*    sum    = acc + N_NODES;
        unsigned* ticket = (unsigned*)(sum + 1);

        zero_acc<<<(N_NODES + 255) / 256, 256, 0, stream>>>(acc, sum, ticket);
        edge_scatter4<<<(N_EDGES / 4 + 255) / 256, 256, 0, stream>>>(li, w, row, col, acc);
        relu_sum_fin<<<49, 256, 0, stream>>>(acc, sum, ticket, out);
    }
}